// Round 2
// baseline (845.281 us; speedup 1.0000x reference)
//
#include <hip/hip_runtime.h>

typedef unsigned short u16;
typedef unsigned int   u32;
typedef __attribute__((ext_vector_type(8))) short bf16x8;
typedef __attribute__((ext_vector_type(4))) float f32x4;

#define MFMA16(a, b, c) __builtin_amdgcn_mfma_f32_16x16x32_bf16((a), (b), (c), 0, 0, 0)

__device__ __forceinline__ float bfu(u16 x) { return __uint_as_float(((u32)x) << 16); }
__device__ __forceinline__ u16 f2bf(float f) {
    u32 u = __float_as_uint(f);
    u32 r = u + 0x7fffu + ((u >> 16) & 1u);   // RNE
    return (u16)(r >> 16);
}
__device__ __forceinline__ u32 pk2(float a, float b) {
    return (u32)f2bf(a) | ((u32)f2bf(b) << 16);
}
__device__ __forceinline__ u32 bfmul2(u32 a, u32 b) {
    float lo = bfu((u16)(a & 0xffffu)) * bfu((u16)(b & 0xffffu));
    float hi = bfu((u16)(a >> 16))     * bfu((u16)(b >> 16));
    return pk2(lo, hi);
}
__device__ __forceinline__ bf16x8 cvt8(float4 a, float4 b) {
    bf16x8 r;
    r[0] = (short)f2bf(a.x); r[1] = (short)f2bf(a.y);
    r[2] = (short)f2bf(a.z); r[3] = (short)f2bf(a.w);
    r[4] = (short)f2bf(b.x); r[5] = (short)f2bf(b.y);
    r[6] = (short)f2bf(b.z); r[7] = (short)f2bf(b.w);
    return r;
}

// ---------------------------------------------------------------------------
// fp32 -> bf16 conversion for 7 tensors of 1M elements each.
// 64 blocks per tensor, 16384 elements per block.
// ---------------------------------------------------------------------------
struct CvtArgs { const float* src[7]; u16* dst[7]; };

__global__ __launch_bounds__(256) void convert_bf16(CvtArgs a) {
    const int tsel = blockIdx.x >> 6;
    const int blk  = blockIdx.x & 63;
    const float* s = a.src[tsel];
    u16* d = a.dst[tsel];
    const int base = blk * 16384;
    #pragma unroll 4
    for (int it = 0; it < 16; ++it) {
        const int idx = base + (it * 256 + threadIdx.x) * 4;
        float4 v = *(const float4*)(s + idx);
        uint2 p;
        p.x = pk2(v.x, v.y);
        p.y = pk2(v.z, v.w);
        *(uint2*)(d + idx) = p;
    }
}

// ---------------------------------------------------------------------------
// 1024x1024x1024 GEMM: C[m,n] = sum_k A[m,k] * W[n,k]   (x @ W.T), bf16 MFMA.
// AMODE 0: A = Ab (bf16). AMODE 1: A = Ab * Gb elementwise (bf16 pair).
// OMODE 0: fp32 out. OMODE 1: bf16 out. OMODE 2: bf16 out transposed C[n][m].
// ---------------------------------------------------------------------------
template<int AMODE, int OMODE, bool BIASF, bool SIGF>
__global__ __launch_bounds__(256) void gemm64(
    const u16* __restrict__ Ab, const u16* __restrict__ Gb,
    const u16* __restrict__ W, const float* __restrict__ biasv,
    void* __restrict__ Cp)
{
    __shared__ u16 lA[64 * 40];   // 64 rows x 32 k, stride 40 (bank pad)
    __shared__ u16 lB[64 * 40];
    const int t = threadIdx.x;
    const int lane = t & 63, w = t >> 6;
    const int ln = lane & 15, q4 = lane >> 4;
    const int wm = (w & 1) * 32, wn = (w >> 1) * 32;
    const int m0 = blockIdx.y * 64, n0 = blockIdx.x * 64;
    const int lrow = t >> 2, lk = (t & 3) * 8;

    f32x4 acc00 = {0,0,0,0}, acc01 = {0,0,0,0}, acc10 = {0,0,0,0}, acc11 = {0,0,0,0};

    for (int k0 = 0; k0 < 1024; k0 += 32) {
        const int idx = (m0 + lrow) * 1024 + k0 + lk;
        uint4 ra = *(const uint4*)(Ab + idx);
        if (AMODE == 1) {
            uint4 rg = *(const uint4*)(Gb + idx);
            ra.x = bfmul2(ra.x, rg.x);
            ra.y = bfmul2(ra.y, rg.y);
            ra.z = bfmul2(ra.z, rg.z);
            ra.w = bfmul2(ra.w, rg.w);
        }
        uint4 rb = *(const uint4*)(W + (n0 + lrow) * 1024 + k0 + lk);
        *(uint4*)(lA + lrow * 40 + lk) = ra;
        *(uint4*)(lB + lrow * 40 + lk) = rb;
        __syncthreads();

        bf16x8 af0 = *(const bf16x8*)(lA + (wm +      ln) * 40 + q4 * 8);
        bf16x8 af1 = *(const bf16x8*)(lA + (wm + 16 + ln) * 40 + q4 * 8);
        bf16x8 bf0 = *(const bf16x8*)(lB + (wn +      ln) * 40 + q4 * 8);
        bf16x8 bf1 = *(const bf16x8*)(lB + (wn + 16 + ln) * 40 + q4 * 8);
        acc00 = MFMA16(af0, bf0, acc00);
        acc01 = MFMA16(af0, bf1, acc01);
        acc10 = MFMA16(af1, bf0, acc10);
        acc11 = MFMA16(af1, bf1, acc11);
        __syncthreads();
    }

    // epilogue: C row = q4*4+r, col = ln  (m89/m91-verified mapping)
    #pragma unroll
    for (int tm = 0; tm < 2; ++tm) {
        #pragma unroll
        for (int tn = 0; tn < 2; ++tn) {
            const f32x4 a = (tm == 0) ? (tn == 0 ? acc00 : acc01)
                                      : (tn == 0 ? acc10 : acc11);
            #pragma unroll
            for (int r = 0; r < 4; ++r) {
                const int gm = m0 + wm + tm * 16 + q4 * 4 + r;
                const int gn = n0 + wn + tn * 16 + ln;
                float cv = a[r];
                if (BIASF) cv += biasv[gn];
                if (SIGF)  cv = 1.0f / (1.0f + __expf(-cv));
                if (OMODE == 0)      ((float*)Cp)[gm * 1024 + gn] = cv;
                else if (OMODE == 1) ((u16*)Cp)[gm * 1024 + gn] = f2bf(cv);
                else                 ((u16*)Cp)[gn * 1024 + gm] = f2bf(cv);
            }
        }
    }
}

// ---------------------------------------------------------------------------
// z[h][i][j] = sum_c bias[i,j,c] * Wz[c,h]   ([1M x 128] @ [128 x 16])
// fp32 bias read straight from global (32B/lane per MFMA), converted inline;
// Wz fragments in registers; LDS transpose for coalesced bf16 z stores.
// 512 (i,j)-rows per block.
// ---------------------------------------------------------------------------
__global__ __launch_bounds__(256) void zproj(
    const float* __restrict__ bias, const float* __restrict__ Wz, u16* __restrict__ z)
{
    __shared__ float lz[16 * 516];
    const int t = threadIdx.x, lane = t & 63, w = t >> 6;
    const int ln = lane & 15, q4 = lane >> 4;
    const int row0 = blockIdx.x * 512;

    bf16x8 bfrag[4];
    #pragma unroll
    for (int kb = 0; kb < 4; ++kb)
        #pragma unroll
        for (int j = 0; j < 8; ++j)
            bfrag[kb][j] = (short)f2bf(Wz[(kb * 32 + q4 * 8 + j) * 16 + ln]);

    #pragma unroll 1
    for (int it = 0; it < 8; ++it) {
        const int rloc = (it * 4 + w) * 16;
        const float* ap = bias + (size_t)(row0 + rloc + ln) * 128 + q4 * 8;
        f32x4 c = {0, 0, 0, 0};
        #pragma unroll
        for (int kb = 0; kb < 4; ++kb) {
            float4 x0 = *(const float4*)(ap + kb * 32);
            float4 x1 = *(const float4*)(ap + kb * 32 + 4);
            bf16x8 a = cvt8(x0, x1);
            c = MFMA16(a, bfrag[kb], c);
        }
        #pragma unroll
        for (int r = 0; r < 4; ++r)
            lz[ln * 516 + rloc + q4 * 4 + r] = c[r];
    }
    __syncthreads();
    #pragma unroll 4
    for (int rep = 0; rep < 32; ++rep) {
        const int idx = rep * 256 + t;
        const int hh = idx >> 9, r = idx & 511;
        z[(size_t)hh * 1048576 + row0 + r] = f2bf(lz[hh * 516 + r]);
    }
}

// ---------------------------------------------------------------------------
// Attention: one block = (h, 16-row i-tile). QK^T via MFMA (q frags in regs,
// k frags from global), softmax in regs + shfl + cross-wave LDS reduce,
// P -> bf16 LDS (stride 1032), PV via MFMA (vT frags from global).
// ---------------------------------------------------------------------------
__global__ __launch_bounds__(256) void attn_kernel(
    const u16* __restrict__ qb, const u16* __restrict__ kb,
    const u16* __restrict__ vT, const u16* __restrict__ zb,
    const float* __restrict__ maskb, u16* __restrict__ o)
{
    __shared__ u16 pbf[16 * 1032];
    __shared__ float redm[4][16];
    __shared__ float reds[4][16];
    const int h = blockIdx.y;
    const int i0 = blockIdx.x * 16;
    const int t = threadIdx.x, lane = t & 63, w = t >> 6;
    const int ln = lane & 15, q4 = lane >> 4;

    const u16* qp = qb + (i0 + ln) * 1024 + h * 64 + q4 * 8;
    const bf16x8 aq0 = *(const bf16x8*)(qp);
    const bf16x8 aq1 = *(const bf16x8*)(qp + 32);

    f32x4 s[16];
    #pragma unroll
    for (int u = 0; u < 16; ++u) {
        const int j0 = (w * 16 + u) * 16;
        const u16* kp = kb + (j0 + ln) * 1024 + h * 64 + q4 * 8;
        bf16x8 b0 = *(const bf16x8*)(kp);
        bf16x8 b1 = *(const bf16x8*)(kp + 32);
        f32x4 c = {0, 0, 0, 0};
        c = MFMA16(aq0, b0, c);
        c = MFMA16(aq1, b1, c);
        const int j = j0 + ln;
        const float mt = (1.0f - maskb[j]) * (-1000000.0f);
        #pragma unroll
        for (int r = 0; r < 4; ++r) {
            const int gi = i0 + q4 * 4 + r;
            c[r] = c[r] * 0.125f + bfu(zb[(size_t)h * 1048576 + gi * 1024 + j]) + mt;
        }
        s[u] = c;
    }

    // row max (each quad's 16 lanes hold 16 j-columns of rows q4*4..q4*4+3)
    float mx[4];
    #pragma unroll
    for (int r = 0; r < 4; ++r) {
        float m_ = s[0][r];
        #pragma unroll
        for (int u = 1; u < 16; ++u) m_ = fmaxf(m_, s[u][r]);
        #pragma unroll
        for (int off = 1; off < 16; off <<= 1) m_ = fmaxf(m_, __shfl_xor(m_, off));
        mx[r] = m_;
    }
    if (ln == 0) {
        #pragma unroll
        for (int r = 0; r < 4; ++r) redm[w][q4 * 4 + r] = mx[r];
    }
    __syncthreads();

    float inv[4];
    #pragma unroll
    for (int r = 0; r < 4; ++r) {
        const int row = q4 * 4 + r;
        const float m_ = fmaxf(fmaxf(redm[0][row], redm[1][row]),
                               fmaxf(redm[2][row], redm[3][row]));
        float s_ = 0.f;
        #pragma unroll
        for (int u = 0; u < 16; ++u) {
            float e = __expf(s[u][r] - m_);
            s[u][r] = e;
            s_ += e;
        }
        #pragma unroll
        for (int off = 1; off < 16; off <<= 1) s_ += __shfl_xor(s_, off);
        mx[r] = s_;
    }
    if (ln == 0) {
        #pragma unroll
        for (int r = 0; r < 4; ++r) reds[w][q4 * 4 + r] = mx[r];
    }
    __syncthreads();
    #pragma unroll
    for (int r = 0; r < 4; ++r) {
        const int row = q4 * 4 + r;
        inv[r] = 1.0f / (reds[0][row] + reds[1][row] + reds[2][row] + reds[3][row]);
    }

    // write P (bf16) into LDS
    #pragma unroll
    for (int u = 0; u < 16; ++u) {
        const int j0 = (w * 16 + u) * 16;
        #pragma unroll
        for (int r = 0; r < 4; ++r)
            pbf[(q4 * 4 + r) * 1032 + j0 + ln] = f2bf(s[u][r] * inv[r]);
    }
    __syncthreads();

    // PV: wave w owns d-tile w
    f32x4 oc = {0, 0, 0, 0};
    #pragma unroll 4
    for (int ks = 0; ks < 32; ++ks) {
        bf16x8 pa = *(const bf16x8*)(pbf + ln * 1032 + ks * 32 + q4 * 8);
        bf16x8 vb = *(const bf16x8*)(vT + (h * 64 + w * 16 + ln) * 1024 + ks * 32 + q4 * 8);
        oc = MFMA16(pa, vb, oc);
    }
    #pragma unroll
    for (int r = 0; r < 4; ++r)
        o[(i0 + q4 * 4 + r) * 1024 + h * 64 + w * 16 + ln] = f2bf(oc[r]);
}

// ---------------------------------------------------------------------------
extern "C" void kernel_launch(void* const* d_in, const int* in_sizes, int n_in,
                              void* d_out, int out_size, void* d_ws, size_t ws_size,
                              hipStream_t stream)
{
    const float* s_in = (const float*)d_in[0];
    const float* k_in = (const float*)d_in[1];
    const float* mask = (const float*)d_in[2];
    const float* bias = (const float*)d_in[3];
    const float* Wq   = (const float*)d_in[4];
    const float* bq   = (const float*)d_in[5];
    const float* Wk   = (const float*)d_in[6];
    const float* Wv   = (const float*)d_in[7];
    const float* Wg   = (const float*)d_in[8];
    const float* Wo   = (const float*)d_in[9];
    const float* Wz   = (const float*)d_in[10];
    // d_in[11] = multiplicity (=1), unused

    char* ws = (char*)d_ws;
    const size_t MB = 1 << 20;
    u16* sb  = (u16*)(ws + 0 * MB);
    u16* kbf = (u16*)(ws + 2 * MB);
    u16* Wqb = (u16*)(ws + 4 * MB);
    u16* Wkb = (u16*)(ws + 6 * MB);
    u16* Wvb = (u16*)(ws + 8 * MB);
    u16* Wgb = (u16*)(ws + 10 * MB);
    u16* Wob = (u16*)(ws + 12 * MB);
    u16* q   = (u16*)(ws + 14 * MB);   // bf16 [i][h*64+d]
    u16* kk  = (u16*)(ws + 16 * MB);   // bf16 [j][h*64+d]
    u16* vT  = (u16*)(ws + 18 * MB);   // bf16 [h*64+d][j]
    u16* g   = (u16*)(ws + 20 * MB);   // bf16 [i][c]
    u16* o   = (u16*)(ws + 22 * MB);   // bf16 [i][h*64+d]
    u16* z   = (u16*)(ws + 24 * MB);   // bf16 [h][i][j]  (32 MB)
    float* out = (float*)d_out;

    CvtArgs ca;
    ca.src[0] = s_in; ca.dst[0] = sb;
    ca.src[1] = k_in; ca.dst[1] = kbf;
    ca.src[2] = Wq;   ca.dst[2] = Wqb;
    ca.src[3] = Wk;   ca.dst[3] = Wkb;
    ca.src[4] = Wv;   ca.dst[4] = Wvb;
    ca.src[5] = Wg;   ca.dst[5] = Wgb;
    ca.src[6] = Wo;   ca.dst[6] = Wob;

    const dim3 gg(16, 16), blk(256);
    hipLaunchKernelGGL(convert_bf16, dim3(448), blk, 0, stream, ca);
    hipLaunchKernelGGL((gemm64<0, 1, true,  false>), gg, blk, 0, stream, sb,  nullptr, Wqb, bq,      q);
    hipLaunchKernelGGL((gemm64<0, 1, false, false>), gg, blk, 0, stream, kbf, nullptr, Wkb, nullptr, kk);
    hipLaunchKernelGGL((gemm64<0, 2, false, false>), gg, blk, 0, stream, kbf, nullptr, Wvb, nullptr, vT);
    hipLaunchKernelGGL((gemm64<0, 1, false, true >), gg, blk, 0, stream, sb,  nullptr, Wgb, nullptr, g);
    hipLaunchKernelGGL(zproj, dim3(2048), blk, 0, stream, bias, Wz, z);
    hipLaunchKernelGGL(attn_kernel, dim3(64, 16), blk, 0, stream, q, kk, vT, z, mask, o);
    hipLaunchKernelGGL((gemm64<1, 0, false, false>), gg, blk, 0, stream, o, g, Wob, nullptr, out);
}

// Round 3
// 814.291 us; speedup vs baseline: 1.0381x; 1.0381x over previous
//
#include <hip/hip_runtime.h>

typedef unsigned short u16;
typedef unsigned int   u32;
typedef __attribute__((ext_vector_type(8))) short bf16x8;
typedef __attribute__((ext_vector_type(4))) float f32x4;

#define MFMA16(a, b, c) __builtin_amdgcn_mfma_f32_16x16x32_bf16((a), (b), (c), 0, 0, 0)

__device__ __forceinline__ float bfu(u16 x) { return __uint_as_float(((u32)x) << 16); }
__device__ __forceinline__ u16 f2bf(float f) {
    u32 u = __float_as_uint(f);
    u32 r = u + 0x7fffu + ((u >> 16) & 1u);   // RNE
    return (u16)(r >> 16);
}
__device__ __forceinline__ u32 pk2(float a, float b) {
    return (u32)f2bf(a) | ((u32)f2bf(b) << 16);
}
__device__ __forceinline__ bf16x8 cvt8(float4 a, float4 b) {
    bf16x8 r;
    r[0] = (short)f2bf(a.x); r[1] = (short)f2bf(a.y);
    r[2] = (short)f2bf(a.z); r[3] = (short)f2bf(a.w);
    r[4] = (short)f2bf(b.x); r[5] = (short)f2bf(b.y);
    r[6] = (short)f2bf(b.z); r[7] = (short)f2bf(b.w);
    return r;
}
// async global->LDS, 16B per lane (dest must be wave-uniform base + lane*16)
__device__ __forceinline__ void gl_lds16(const u16* g, u16* l) {
    __builtin_amdgcn_global_load_lds(
        (const __attribute__((address_space(1))) void*)g,
        (__attribute__((address_space(3))) void*)l, 16, 0, 0);
}

// ---------------------------------------------------------------------------
// fp32 -> bf16 conversion: 7 tensors x 1M elements. 64 blocks/tensor.
// ---------------------------------------------------------------------------
struct CvtArgs { const float* src[7]; u16* dst[7]; };

__global__ __launch_bounds__(256) void convert_bf16(CvtArgs a) {
    const int tsel = blockIdx.x >> 6;
    const int blk  = blockIdx.x & 63;
    const float* s = a.src[tsel];
    u16* d = a.dst[tsel];
    const int base = blk * 16384;
    #pragma unroll 4
    for (int it = 0; it < 16; ++it) {
        const int idx = base + (it * 256 + threadIdx.x) * 4;
        float4 v = *(const float4*)(s + idx);
        uint2 p;
        p.x = pk2(v.x, v.y);
        p.y = pk2(v.z, v.w);
        *(uint2*)(d + idx) = p;
    }
}

// ---------------------------------------------------------------------------
// Wide GEMM: C[m,n] = sum_k A[m,k] * W[n,k], A bf16 [1024x1024],
// W = two stacked 1024x1024 weight blocks (W0 rows 0..1023, W1 rows 1024..2047).
// 64x64 tile, BK=64, global_load_lds staging (m97 pattern).
// EPI 0: s -> q (bias, bf16) | g (sigmoid, bf16)
// EPI 1: k_in -> k (bf16)    | vT (bf16, transposed)
// EPI 2: o_gated -> out (fp32), N=1024 only
// ---------------------------------------------------------------------------
template<int EPI>
__global__ __launch_bounds__(256) void gemmW(
    const u16* __restrict__ Ab, const u16* __restrict__ W0, const u16* __restrict__ W1,
    const float* __restrict__ bqv, void* __restrict__ C0, void* __restrict__ C1)
{
    __shared__ u16 lA[64 * 64];   // [row][k] 64x64, unpadded (global_load_lds layout)
    __shared__ u16 lB[64 * 64];
    const int t = threadIdx.x, lane = t & 63, w = t >> 6;
    const int ln = lane & 15, q4 = lane >> 4;
    const int wm = (w & 1) * 32, wn = (w >> 1) * 32;
    const int m0 = blockIdx.y * 64, n0 = blockIdx.x * 64;

    const u16* Wp = (n0 < 1024) ? (W0 + (size_t)n0 * 1024)
                                : (W1 + (size_t)(n0 - 1024) * 1024);
    const int srow = t >> 3, scol = (t & 7) * 8;   // staging: row t>>3, col (t&7)*8
    const u16* ga = Ab + (m0 + srow) * 1024 + scol;
    const u16* gb = Wp + srow * 1024 + scol;
    u16* la = lA + t * 8;                           // == srow*64 + scol
    u16* lb = lB + t * 8;

    f32x4 acc00 = {0,0,0,0}, acc01 = {0,0,0,0}, acc10 = {0,0,0,0}, acc11 = {0,0,0,0};

    for (int k0 = 0; k0 < 1024; k0 += 64) {
        gl_lds16(ga + k0,             la);
        gl_lds16(ga + k0 + 32 * 1024, la + 32 * 64);
        gl_lds16(gb + k0,             lb);
        gl_lds16(gb + k0 + 32 * 1024, lb + 32 * 64);
        __syncthreads();
        #pragma unroll
        for (int ks = 0; ks < 2; ++ks) {
            bf16x8 a0 = *(const bf16x8*)(lA + (wm +      ln) * 64 + ks * 32 + q4 * 8);
            bf16x8 a1 = *(const bf16x8*)(lA + (wm + 16 + ln) * 64 + ks * 32 + q4 * 8);
            bf16x8 b0 = *(const bf16x8*)(lB + (wn +      ln) * 64 + ks * 32 + q4 * 8);
            bf16x8 b1 = *(const bf16x8*)(lB + (wn + 16 + ln) * 64 + ks * 32 + q4 * 8);
            acc00 = MFMA16(a0, b0, acc00);
            acc01 = MFMA16(a0, b1, acc01);
            acc10 = MFMA16(a1, b0, acc10);
            acc11 = MFMA16(a1, b1, acc11);
        }
        __syncthreads();
    }

    // epilogue: C row = q4*4+r, col = ln (m89/m91-verified mapping)
    #pragma unroll
    for (int tm = 0; tm < 2; ++tm) {
        #pragma unroll
        for (int tn = 0; tn < 2; ++tn) {
            const f32x4 a = (tm == 0) ? (tn == 0 ? acc00 : acc01)
                                      : (tn == 0 ? acc10 : acc11);
            #pragma unroll
            for (int r = 0; r < 4; ++r) {
                const int gm = m0 + wm + tm * 16 + q4 * 4 + r;
                const int gn = n0 + wn + tn * 16 + ln;
                float cv = a[r];
                if (EPI == 0) {
                    if (gn < 1024) ((u16*)C0)[gm * 1024 + gn] = f2bf(cv + bqv[gn]);
                    else ((u16*)C1)[gm * 1024 + gn - 1024] =
                             f2bf(1.0f / (1.0f + __expf(-cv)));
                } else if (EPI == 1) {
                    if (gn < 1024) ((u16*)C0)[gm * 1024 + gn] = f2bf(cv);
                    else ((u16*)C1)[(gn - 1024) * 1024 + gm] = f2bf(cv);
                } else {
                    ((float*)C0)[gm * 1024 + gn] = cv;
                }
            }
        }
    }
}

// ---------------------------------------------------------------------------
// z[h][i][j] = sum_c bias[i,j,c] * Wz[c,h]   ([1M x 128] @ [128 x 16])
// fp32 bias straight from global (32B/lane per MFMA), converted inline;
// Wz fragments in registers; LDS transpose for coalesced bf16 z stores.
// ---------------------------------------------------------------------------
__global__ __launch_bounds__(256) void zproj(
    const float* __restrict__ bias, const float* __restrict__ Wz, u16* __restrict__ z)
{
    __shared__ float lz[16 * 516];
    const int t = threadIdx.x, lane = t & 63, w = t >> 6;
    const int ln = lane & 15, q4 = lane >> 4;
    const int row0 = blockIdx.x * 512;

    bf16x8 bfrag[4];
    #pragma unroll
    for (int kb = 0; kb < 4; ++kb)
        #pragma unroll
        for (int j = 0; j < 8; ++j)
            bfrag[kb][j] = (short)f2bf(Wz[(kb * 32 + q4 * 8 + j) * 16 + ln]);

    #pragma unroll 1
    for (int it = 0; it < 8; ++it) {
        const int rloc = (it * 4 + w) * 16;
        const float* ap = bias + (size_t)(row0 + rloc + ln) * 128 + q4 * 8;
        f32x4 c = {0, 0, 0, 0};
        #pragma unroll
        for (int kb = 0; kb < 4; ++kb) {
            float4 x0 = *(const float4*)(ap + kb * 32);
            float4 x1 = *(const float4*)(ap + kb * 32 + 4);
            bf16x8 a = cvt8(x0, x1);
            c = MFMA16(a, bfrag[kb], c);
        }
        #pragma unroll
        for (int r = 0; r < 4; ++r)
            lz[ln * 516 + rloc + q4 * 4 + r] = c[r];
    }
    __syncthreads();
    #pragma unroll 4
    for (int rep = 0; rep < 32; ++rep) {
        const int idx = rep * 256 + t;
        const int hh = idx >> 9, r = idx & 511;
        z[(size_t)hh * 1048576 + row0 + r] = f2bf(lz[hh * 516 + r]);
    }
}

// ---------------------------------------------------------------------------
// Attention: one block = (h, 16-row i-tile). QK^T via MFMA (q frags in regs,
// k frags from global), softmax in regs + shfl + cross-wave LDS reduce,
// P -> bf16 LDS (stride 1032), PV via MFMA (vT frags from global).
// Epilogue applies the sigmoid gate: o_gated = g * o (bf16 out).
// ---------------------------------------------------------------------------
__global__ __launch_bounds__(256) void attn_kernel(
    const u16* __restrict__ qb, const u16* __restrict__ kmat,
    const u16* __restrict__ vT, const u16* __restrict__ zb,
    const float* __restrict__ maskb, const u16* __restrict__ gmat,
    u16* __restrict__ o)
{
    __shared__ u16 pbf[16 * 1032];
    __shared__ float redm[4][16];
    __shared__ float reds[4][16];
    const int h = blockIdx.y;
    const int i0 = blockIdx.x * 16;
    const int t = threadIdx.x, lane = t & 63, w = t >> 6;
    const int ln = lane & 15, q4 = lane >> 4;

    const u16* qp = qb + (i0 + ln) * 1024 + h * 64 + q4 * 8;
    const bf16x8 aq0 = *(const bf16x8*)(qp);
    const bf16x8 aq1 = *(const bf16x8*)(qp + 32);

    f32x4 s[16];
    #pragma unroll
    for (int u = 0; u < 16; ++u) {
        const int j0 = (w * 16 + u) * 16;
        const u16* kp = kmat + (j0 + ln) * 1024 + h * 64 + q4 * 8;
        bf16x8 b0 = *(const bf16x8*)(kp);
        bf16x8 b1 = *(const bf16x8*)(kp + 32);
        f32x4 c = {0, 0, 0, 0};
        c = MFMA16(aq0, b0, c);
        c = MFMA16(aq1, b1, c);
        const int j = j0 + ln;
        const float mt = (1.0f - maskb[j]) * (-1000000.0f);
        #pragma unroll
        for (int r = 0; r < 4; ++r) {
            const int gi = i0 + q4 * 4 + r;
            c[r] = c[r] * 0.125f + bfu(zb[(size_t)h * 1048576 + gi * 1024 + j]) + mt;
        }
        s[u] = c;
    }

    float mx[4];
    #pragma unroll
    for (int r = 0; r < 4; ++r) {
        float m_ = s[0][r];
        #pragma unroll
        for (int u = 1; u < 16; ++u) m_ = fmaxf(m_, s[u][r]);
        #pragma unroll
        for (int off = 1; off < 16; off <<= 1) m_ = fmaxf(m_, __shfl_xor(m_, off));
        mx[r] = m_;
    }
    if (ln == 0) {
        #pragma unroll
        for (int r = 0; r < 4; ++r) redm[w][q4 * 4 + r] = mx[r];
    }
    __syncthreads();

    float inv[4];
    #pragma unroll
    for (int r = 0; r < 4; ++r) {
        const int row = q4 * 4 + r;
        const float m_ = fmaxf(fmaxf(redm[0][row], redm[1][row]),
                               fmaxf(redm[2][row], redm[3][row]));
        float s_ = 0.f;
        #pragma unroll
        for (int u = 0; u < 16; ++u) {
            float e = __expf(s[u][r] - m_);
            s[u][r] = e;
            s_ += e;
        }
        #pragma unroll
        for (int off = 1; off < 16; off <<= 1) s_ += __shfl_xor(s_, off);
        mx[r] = s_;
    }
    if (ln == 0) {
        #pragma unroll
        for (int r = 0; r < 4; ++r) reds[w][q4 * 4 + r] = mx[r];
    }
    __syncthreads();
    #pragma unroll
    for (int r = 0; r < 4; ++r) {
        const int row = q4 * 4 + r;
        inv[r] = 1.0f / (reds[0][row] + reds[1][row] + reds[2][row] + reds[3][row]);
    }

    #pragma unroll
    for (int u = 0; u < 16; ++u) {
        const int j0 = (w * 16 + u) * 16;
        #pragma unroll
        for (int r = 0; r < 4; ++r)
            pbf[(q4 * 4 + r) * 1032 + j0 + ln] = f2bf(s[u][r] * inv[r]);
    }
    __syncthreads();

    f32x4 oc = {0, 0, 0, 0};
    #pragma unroll 4
    for (int ks = 0; ks < 32; ++ks) {
        bf16x8 pa = *(const bf16x8*)(pbf + ln * 1032 + ks * 32 + q4 * 8);
        bf16x8 vb = *(const bf16x8*)(vT + (h * 64 + w * 16 + ln) * 1024 + ks * 32 + q4 * 8);
        oc = MFMA16(pa, vb, oc);
    }
    const int col = h * 64 + w * 16 + ln;
    #pragma unroll
    for (int r = 0; r < 4; ++r) {
        const int gi = i0 + q4 * 4 + r;
        const float gv = bfu(gmat[gi * 1024 + col]);
        o[gi * 1024 + col] = f2bf(oc[r] * gv);
    }
}

// ---------------------------------------------------------------------------
extern "C" void kernel_launch(void* const* d_in, const int* in_sizes, int n_in,
                              void* d_out, int out_size, void* d_ws, size_t ws_size,
                              hipStream_t stream)
{
    const float* s_in = (const float*)d_in[0];
    const float* k_in = (const float*)d_in[1];
    const float* mask = (const float*)d_in[2];
    const float* bias = (const float*)d_in[3];
    const float* Wq   = (const float*)d_in[4];
    const float* bq   = (const float*)d_in[5];
    const float* Wk   = (const float*)d_in[6];
    const float* Wv   = (const float*)d_in[7];
    const float* Wg   = (const float*)d_in[8];
    const float* Wo   = (const float*)d_in[9];
    const float* Wz   = (const float*)d_in[10];
    // d_in[11] = multiplicity (=1), unused

    char* ws = (char*)d_ws;
    const size_t MB = 1 << 20;
    u16* sb  = (u16*)(ws + 0 * MB);
    u16* kbf = (u16*)(ws + 2 * MB);
    u16* Wqb = (u16*)(ws + 4 * MB);
    u16* Wkb = (u16*)(ws + 6 * MB);
    u16* Wvb = (u16*)(ws + 8 * MB);
    u16* Wgb = (u16*)(ws + 10 * MB);
    u16* Wob = (u16*)(ws + 12 * MB);
    u16* q   = (u16*)(ws + 14 * MB);   // bf16 [i][h*64+d]
    u16* kk  = (u16*)(ws + 16 * MB);   // bf16 [j][h*64+d]
    u16* vT  = (u16*)(ws + 18 * MB);   // bf16 [h*64+d][j]
    u16* g   = (u16*)(ws + 20 * MB);   // bf16 [i][c] (sigmoid gate)
    u16* og  = (u16*)(ws + 22 * MB);   // bf16 gated attention output
    u16* z   = (u16*)(ws + 24 * MB);   // bf16 [h][i][j] (32 MB)
    float* out = (float*)d_out;

    CvtArgs ca;
    ca.src[0] = s_in; ca.dst[0] = sb;
    ca.src[1] = k_in; ca.dst[1] = kbf;
    ca.src[2] = Wq;   ca.dst[2] = Wqb;
    ca.src[3] = Wk;   ca.dst[3] = Wkb;
    ca.src[4] = Wv;   ca.dst[4] = Wvb;
    ca.src[5] = Wg;   ca.dst[5] = Wgb;
    ca.src[6] = Wo;   ca.dst[6] = Wob;

    const dim3 blk(256);
    hipLaunchKernelGGL(convert_bf16, dim3(448), blk, 0, stream, ca);
    hipLaunchKernelGGL(gemmW<0>, dim3(32, 16), blk, 0, stream, sb,  Wqb, Wgb, bq, q,  g);
    hipLaunchKernelGGL(gemmW<1>, dim3(32, 16), blk, 0, stream, kbf, Wkb, Wvb, nullptr, kk, vT);
    hipLaunchKernelGGL(zproj, dim3(2048), blk, 0, stream, bias, Wz, z);
    hipLaunchKernelGGL(attn_kernel, dim3(64, 16), blk, 0, stream, q, kk, vT, z, mask, g, og);
    hipLaunchKernelGGL(gemmW<2>, dim3(16, 16), blk, 0, stream, og, Wob, nullptr, nullptr, out, nullptr);
}

// Round 4
// 801.353 us; speedup vs baseline: 1.0548x; 1.0161x over previous
//
#include <hip/hip_runtime.h>

typedef unsigned short u16;
typedef unsigned int   u32;
typedef __attribute__((ext_vector_type(8))) short bf16x8;
typedef __attribute__((ext_vector_type(4))) float f32x4;

#define MFMA16(a, b, c) __builtin_amdgcn_mfma_f32_16x16x32_bf16((a), (b), (c), 0, 0, 0)

__device__ __forceinline__ float bfu(u16 x) { return __uint_as_float(((u32)x) << 16); }
__device__ __forceinline__ u16 f2bf(float f) {
    u32 u = __float_as_uint(f);
    u32 r = u + 0x7fffu + ((u >> 16) & 1u);   // RNE
    return (u16)(r >> 16);
}
__device__ __forceinline__ u32 pk2(float a, float b) {
    return (u32)f2bf(a) | ((u32)f2bf(b) << 16);
}
__device__ __forceinline__ bf16x8 cvt8(float4 a, float4 b) {
    bf16x8 r;
    r[0] = (short)f2bf(a.x); r[1] = (short)f2bf(a.y);
    r[2] = (short)f2bf(a.z); r[3] = (short)f2bf(a.w);
    r[4] = (short)f2bf(b.x); r[5] = (short)f2bf(b.y);
    r[6] = (short)f2bf(b.z); r[7] = (short)f2bf(b.w);
    return r;
}
// async global->LDS, 16B per lane (dest = wave-uniform base + lane*16)
__device__ __forceinline__ void gl_lds16(const u16* g, u16* l) {
    __builtin_amdgcn_global_load_lds(
        (const __attribute__((address_space(1))) void*)g,
        (__attribute__((address_space(3))) void*)l, 16, 0, 0);
}

struct CvtArgs { const float* src[7]; u16* dst[7]; };

// ---------------------------------------------------------------------------
// Fused launch 1:
//   blocks [0,2048):    z[h][i][j] = sum_c bias[i,j,c]*Wz[c,h]  (MFMA, fp32
//                       bias straight from global, LDS transpose, bf16 out)
//   blocks [2048,2496): fp32->bf16 convert, 7 tensors x 1M elems, 64 blk each
// ---------------------------------------------------------------------------
__global__ __launch_bounds__(256) void zproj_cvt(
    const float* __restrict__ bias, const float* __restrict__ Wz,
    u16* __restrict__ z, CvtArgs ca)
{
    __shared__ float lz[16 * 516];
    const int t = threadIdx.x;

    if (blockIdx.x >= 2048) {               // ---- convert part ----
        const int blk  = blockIdx.x - 2048;
        const int tsel = blk >> 6;
        const float* s = ca.src[tsel];
        u16* d = ca.dst[tsel];
        const int base = (blk & 63) * 16384;
        #pragma unroll 4
        for (int it = 0; it < 16; ++it) {
            const int idx = base + (it * 256 + t) * 4;
            float4 v = *(const float4*)(s + idx);
            uint2 p;
            p.x = pk2(v.x, v.y);
            p.y = pk2(v.z, v.w);
            *(uint2*)(d + idx) = p;
        }
        return;
    }

    // ---- zproj part ----
    const int lane = t & 63, w = t >> 6;
    const int ln = lane & 15, q4 = lane >> 4;
    const int row0 = blockIdx.x * 512;

    bf16x8 bfrag[4];
    #pragma unroll
    for (int kb = 0; kb < 4; ++kb)
        #pragma unroll
        for (int j = 0; j < 8; ++j)
            bfrag[kb][j] = (short)f2bf(Wz[(kb * 32 + q4 * 8 + j) * 16 + ln]);

    #pragma unroll 1
    for (int it = 0; it < 8; ++it) {
        const int rloc = (it * 4 + w) * 16;
        const float* ap = bias + (size_t)(row0 + rloc + ln) * 128 + q4 * 8;
        f32x4 c = {0, 0, 0, 0};
        #pragma unroll
        for (int kb = 0; kb < 4; ++kb) {
            float4 x0 = *(const float4*)(ap + kb * 32);
            float4 x1 = *(const float4*)(ap + kb * 32 + 4);
            bf16x8 a = cvt8(x0, x1);
            c = MFMA16(a, bfrag[kb], c);
        }
        #pragma unroll
        for (int r = 0; r < 4; ++r)
            lz[ln * 516 + rloc + q4 * 4 + r] = c[r];
    }
    __syncthreads();
    #pragma unroll 4
    for (int rep = 0; rep < 32; ++rep) {
        const int idx = rep * 256 + t;
        const int hh = idx >> 9, r = idx & 511;
        z[(size_t)hh * 1048576 + row0 + r] = f2bf(lz[hh * 516 + r]);
    }
}

// ---------------------------------------------------------------------------
// Merged QKVG GEMM (grid 32x16x2 = 1024 blocks, 4 blocks/CU):
//  z=0: A=s_bf16,   W=[Wq|Wg]: n<1024 -> q (bias, bf16); else g (sigmoid, bf16)
//  z=1: A=kin_bf16, W=[Wk|Wv]: n<1024 -> k (bf16);      else vT (bf16 transp.)
// 64x64 tile, BK=64, global_load_lds staging (m97 pattern).
// ---------------------------------------------------------------------------
__global__ __launch_bounds__(256) void gemm_qkvg(
    const u16* __restrict__ sb, const u16* __restrict__ kbf,
    const u16* __restrict__ Wqb, const u16* __restrict__ Wgb,
    const u16* __restrict__ Wkb, const u16* __restrict__ Wvb,
    const float* __restrict__ bqv,
    u16* __restrict__ q, u16* __restrict__ g,
    u16* __restrict__ kk, u16* __restrict__ vT)
{
    __shared__ u16 lA[64 * 64];
    __shared__ u16 lB[64 * 64];
    const int zb = blockIdx.z;
    const u16* Ab = zb ? kbf : sb;
    const u16* W0 = zb ? Wkb : Wqb;
    const u16* W1 = zb ? Wvb : Wgb;

    const int t = threadIdx.x, lane = t & 63, w = t >> 6;
    const int ln = lane & 15, q4 = lane >> 4;
    const int wm = (w & 1) * 32, wn = (w >> 1) * 32;
    const int m0 = blockIdx.y * 64, n0 = blockIdx.x * 64;

    const u16* Wp = (n0 < 1024) ? (W0 + (size_t)n0 * 1024)
                                : (W1 + (size_t)(n0 - 1024) * 1024);
    const int srow = t >> 3, scol = (t & 7) * 8;
    const u16* ga = Ab + (m0 + srow) * 1024 + scol;
    const u16* gb = Wp + srow * 1024 + scol;
    u16* la = lA + t * 8;
    u16* lb = lB + t * 8;

    f32x4 acc00 = {0,0,0,0}, acc01 = {0,0,0,0}, acc10 = {0,0,0,0}, acc11 = {0,0,0,0};

    for (int k0 = 0; k0 < 1024; k0 += 64) {
        gl_lds16(ga + k0,             la);
        gl_lds16(ga + k0 + 32 * 1024, la + 32 * 64);
        gl_lds16(gb + k0,             lb);
        gl_lds16(gb + k0 + 32 * 1024, lb + 32 * 64);
        __syncthreads();
        #pragma unroll
        for (int ks = 0; ks < 2; ++ks) {
            bf16x8 a0 = *(const bf16x8*)(lA + (wm +      ln) * 64 + ks * 32 + q4 * 8);
            bf16x8 a1 = *(const bf16x8*)(lA + (wm + 16 + ln) * 64 + ks * 32 + q4 * 8);
            bf16x8 b0 = *(const bf16x8*)(lB + (wn +      ln) * 64 + ks * 32 + q4 * 8);
            bf16x8 b1 = *(const bf16x8*)(lB + (wn + 16 + ln) * 64 + ks * 32 + q4 * 8);
            acc00 = MFMA16(a0, b0, acc00);
            acc01 = MFMA16(a0, b1, acc01);
            acc10 = MFMA16(a1, b0, acc10);
            acc11 = MFMA16(a1, b1, acc11);
        }
        __syncthreads();
    }

    #pragma unroll
    for (int tm = 0; tm < 2; ++tm) {
        #pragma unroll
        for (int tn = 0; tn < 2; ++tn) {
            const f32x4 a = (tm == 0) ? (tn == 0 ? acc00 : acc01)
                                      : (tn == 0 ? acc10 : acc11);
            #pragma unroll
            for (int r = 0; r < 4; ++r) {
                const int gm = m0 + wm + tm * 16 + q4 * 4 + r;
                const int gn = n0 + wn + tn * 16 + ln;
                float cv = a[r];
                if (zb == 0) {
                    if (gn < 1024) q[gm * 1024 + gn] = f2bf(cv + bqv[gn]);
                    else g[gm * 1024 + gn - 1024] = f2bf(1.0f / (1.0f + __expf(-cv)));
                } else {
                    if (gn < 1024) kk[gm * 1024 + gn] = f2bf(cv);
                    else vT[(gn - 1024) * 1024 + gm] = f2bf(cv);
                }
            }
        }
    }
}

// ---------------------------------------------------------------------------
// Attention: one block = (h, 16-row i-tile). QK^T via MFMA, softmax in regs,
// P -> bf16 LDS (stride 1032), PV via MFMA; epilogue applies sigmoid gate.
// ---------------------------------------------------------------------------
__global__ __launch_bounds__(256) void attn_kernel(
    const u16* __restrict__ qb, const u16* __restrict__ kmat,
    const u16* __restrict__ vT, const u16* __restrict__ zb,
    const float* __restrict__ maskb, const u16* __restrict__ gmat,
    u16* __restrict__ o)
{
    __shared__ u16 pbf[16 * 1032];
    __shared__ float redm[4][16];
    __shared__ float reds[4][16];
    const int h = blockIdx.y;
    const int i0 = blockIdx.x * 16;
    const int t = threadIdx.x, lane = t & 63, w = t >> 6;
    const int ln = lane & 15, q4 = lane >> 4;

    const u16* qp = qb + (i0 + ln) * 1024 + h * 64 + q4 * 8;
    const bf16x8 aq0 = *(const bf16x8*)(qp);
    const bf16x8 aq1 = *(const bf16x8*)(qp + 32);

    f32x4 s[16];
    #pragma unroll
    for (int u = 0; u < 16; ++u) {
        const int j0 = (w * 16 + u) * 16;
        const u16* kp = kmat + (j0 + ln) * 1024 + h * 64 + q4 * 8;
        bf16x8 b0 = *(const bf16x8*)(kp);
        bf16x8 b1 = *(const bf16x8*)(kp + 32);
        f32x4 c = {0, 0, 0, 0};
        c = MFMA16(aq0, b0, c);
        c = MFMA16(aq1, b1, c);
        const int j = j0 + ln;
        const float mt = (1.0f - maskb[j]) * (-1000000.0f);
        #pragma unroll
        for (int r = 0; r < 4; ++r) {
            const int gi = i0 + q4 * 4 + r;
            c[r] = c[r] * 0.125f + bfu(zb[(size_t)h * 1048576 + gi * 1024 + j]) + mt;
        }
        s[u] = c;
    }

    float mx[4];
    #pragma unroll
    for (int r = 0; r < 4; ++r) {
        float m_ = s[0][r];
        #pragma unroll
        for (int u = 1; u < 16; ++u) m_ = fmaxf(m_, s[u][r]);
        #pragma unroll
        for (int off = 1; off < 16; off <<= 1) m_ = fmaxf(m_, __shfl_xor(m_, off));
        mx[r] = m_;
    }
    if (ln == 0) {
        #pragma unroll
        for (int r = 0; r < 4; ++r) redm[w][q4 * 4 + r] = mx[r];
    }
    __syncthreads();

    float inv[4];
    #pragma unroll
    for (int r = 0; r < 4; ++r) {
        const int row = q4 * 4 + r;
        const float m_ = fmaxf(fmaxf(redm[0][row], redm[1][row]),
                               fmaxf(redm[2][row], redm[3][row]));
        float s_ = 0.f;
        #pragma unroll
        for (int u = 0; u < 16; ++u) {
            float e = __expf(s[u][r] - m_);
            s[u][r] = e;
            s_ += e;
        }
        #pragma unroll
        for (int off = 1; off < 16; off <<= 1) s_ += __shfl_xor(s_, off);
        mx[r] = s_;
    }
    if (ln == 0) {
        #pragma unroll
        for (int r = 0; r < 4; ++r) reds[w][q4 * 4 + r] = mx[r];
    }
    __syncthreads();
    #pragma unroll
    for (int r = 0; r < 4; ++r) {
        const int row = q4 * 4 + r;
        inv[r] = 1.0f / (reds[0][row] + reds[1][row] + reds[2][row] + reds[3][row]);
    }

    #pragma unroll
    for (int u = 0; u < 16; ++u) {
        const int j0 = (w * 16 + u) * 16;
        #pragma unroll
        for (int r = 0; r < 4; ++r)
            pbf[(q4 * 4 + r) * 1032 + j0 + ln] = f2bf(s[u][r] * inv[r]);
    }
    __syncthreads();

    f32x4 oc = {0, 0, 0, 0};
    #pragma unroll 4
    for (int ks = 0; ks < 32; ++ks) {
        bf16x8 pa = *(const bf16x8*)(pbf + ln * 1032 + ks * 32 + q4 * 8);
        bf16x8 vb = *(const bf16x8*)(vT + (h * 64 + w * 16 + ln) * 1024 + ks * 32 + q4 * 8);
        oc = MFMA16(pa, vb, oc);
    }
    const int col = h * 64 + w * 16 + ln;
    #pragma unroll
    for (int r = 0; r < 4; ++r) {
        const int gi = i0 + q4 * 4 + r;
        const float gv = bfu(gmat[gi * 1024 + col]);
        o[gi * 1024 + col] = f2bf(oc[r] * gv);
    }
}

// ---------------------------------------------------------------------------
// Final GEMM, split-K=4: partial[kz][m][n] = sum_{k in quarter} og[m,k]*Wo[n,k]
// grid (16,16,4) = 1024 blocks. fp32 partials; reduced by reduce4.
// ---------------------------------------------------------------------------
__global__ __launch_bounds__(256) void gemm_out_sk(
    const u16* __restrict__ og, const u16* __restrict__ Wob, float* __restrict__ pbuf)
{
    __shared__ u16 lA[64 * 64];
    __shared__ u16 lB[64 * 64];
    const int t = threadIdx.x, lane = t & 63, w = t >> 6;
    const int ln = lane & 15, q4 = lane >> 4;
    const int wm = (w & 1) * 32, wn = (w >> 1) * 32;
    const int m0 = blockIdx.y * 64, n0 = blockIdx.x * 64;
    const int kz = blockIdx.z;

    const int srow = t >> 3, scol = (t & 7) * 8;
    const u16* ga = og  + (m0 + srow) * 1024 + scol + kz * 256;
    const u16* gb = Wob + (n0 + srow) * 1024 + scol + kz * 256;
    u16* la = lA + t * 8;
    u16* lb = lB + t * 8;

    f32x4 acc00 = {0,0,0,0}, acc01 = {0,0,0,0}, acc10 = {0,0,0,0}, acc11 = {0,0,0,0};

    for (int k0 = 0; k0 < 256; k0 += 64) {
        gl_lds16(ga + k0,             la);
        gl_lds16(ga + k0 + 32 * 1024, la + 32 * 64);
        gl_lds16(gb + k0,             lb);
        gl_lds16(gb + k0 + 32 * 1024, lb + 32 * 64);
        __syncthreads();
        #pragma unroll
        for (int ks = 0; ks < 2; ++ks) {
            bf16x8 a0 = *(const bf16x8*)(lA + (wm +      ln) * 64 + ks * 32 + q4 * 8);
            bf16x8 a1 = *(const bf16x8*)(lA + (wm + 16 + ln) * 64 + ks * 32 + q4 * 8);
            bf16x8 b0 = *(const bf16x8*)(lB + (wn +      ln) * 64 + ks * 32 + q4 * 8);
            bf16x8 b1 = *(const bf16x8*)(lB + (wn + 16 + ln) * 64 + ks * 32 + q4 * 8);
            acc00 = MFMA16(a0, b0, acc00);
            acc01 = MFMA16(a0, b1, acc01);
            acc10 = MFMA16(a1, b0, acc10);
            acc11 = MFMA16(a1, b1, acc11);
        }
        __syncthreads();
    }

    float* pz = pbuf + (size_t)kz * 1048576;
    #pragma unroll
    for (int tm = 0; tm < 2; ++tm) {
        #pragma unroll
        for (int tn = 0; tn < 2; ++tn) {
            const f32x4 a = (tm == 0) ? (tn == 0 ? acc00 : acc01)
                                      : (tn == 0 ? acc10 : acc11);
            #pragma unroll
            for (int r = 0; r < 4; ++r) {
                const int gm = m0 + wm + tm * 16 + q4 * 4 + r;
                const int gn = n0 + wn + tn * 16 + ln;
                pz[gm * 1024 + gn] = a[r];
            }
        }
    }
}

__global__ __launch_bounds__(256) void reduce4(
    const float* __restrict__ p, float* __restrict__ out)
{
    const int idx = (blockIdx.x * 256 + threadIdx.x) * 4;
    float4 a = *(const float4*)(p + idx);
    float4 b = *(const float4*)(p + 1048576 + idx);
    float4 c = *(const float4*)(p + 2097152 + idx);
    float4 d = *(const float4*)(p + 3145728 + idx);
    float4 r;
    r.x = (a.x + b.x) + (c.x + d.x);
    r.y = (a.y + b.y) + (c.y + d.y);
    r.z = (a.z + b.z) + (c.z + d.z);
    r.w = (a.w + b.w) + (c.w + d.w);
    *(float4*)(out + idx) = r;
}

// ---------------------------------------------------------------------------
extern "C" void kernel_launch(void* const* d_in, const int* in_sizes, int n_in,
                              void* d_out, int out_size, void* d_ws, size_t ws_size,
                              hipStream_t stream)
{
    const float* s_in = (const float*)d_in[0];
    const float* k_in = (const float*)d_in[1];
    const float* mask = (const float*)d_in[2];
    const float* bias = (const float*)d_in[3];
    const float* Wq   = (const float*)d_in[4];
    const float* bq   = (const float*)d_in[5];
    const float* Wk   = (const float*)d_in[6];
    const float* Wv   = (const float*)d_in[7];
    const float* Wg   = (const float*)d_in[8];
    const float* Wo   = (const float*)d_in[9];
    const float* Wz   = (const float*)d_in[10];

    char* ws = (char*)d_ws;
    const size_t MB = 1 << 20;
    u16* sb  = (u16*)(ws + 0 * MB);
    u16* kbf = (u16*)(ws + 2 * MB);
    u16* Wqb = (u16*)(ws + 4 * MB);
    u16* Wkb = (u16*)(ws + 6 * MB);
    u16* Wvb = (u16*)(ws + 8 * MB);
    u16* Wgb = (u16*)(ws + 10 * MB);
    u16* Wob = (u16*)(ws + 12 * MB);
    u16* q   = (u16*)(ws + 14 * MB);   // bf16 [i][h*64+d]
    u16* kk  = (u16*)(ws + 16 * MB);   // bf16 [j][h*64+d]
    u16* vT  = (u16*)(ws + 18 * MB);   // bf16 [h*64+d][j]
    u16* g   = (u16*)(ws + 20 * MB);   // bf16 sigmoid gate
    u16* og  = (u16*)(ws + 22 * MB);   // bf16 gated attention output
    u16* z   = (u16*)(ws + 24 * MB);   // bf16 [h][i][j] (32 MB)
    float* pbuf = (float*)(ws + 56 * MB); // fp32 [4][1024][1024] (16 MB)
    float* out = (float*)d_out;

    CvtArgs ca;
    ca.src[0] = s_in; ca.dst[0] = sb;
    ca.src[1] = k_in; ca.dst[1] = kbf;
    ca.src[2] = Wq;   ca.dst[2] = Wqb;
    ca.src[3] = Wk;   ca.dst[3] = Wkb;
    ca.src[4] = Wv;   ca.dst[4] = Wvb;
    ca.src[5] = Wg;   ca.dst[5] = Wgb;
    ca.src[6] = Wo;   ca.dst[6] = Wob;

    const dim3 blk(256);
    hipLaunchKernelGGL(zproj_cvt, dim3(2496), blk, 0, stream, bias, Wz, z, ca);
    hipLaunchKernelGGL(gemm_qkvg, dim3(32, 16, 2), blk, 0, stream,
                       sb, kbf, Wqb, Wgb, Wkb, Wvb, bq, q, g, kk, vT);
    hipLaunchKernelGGL(attn_kernel, dim3(64, 16), blk, 0, stream,
                       q, kk, vT, z, mask, g, og);
    hipLaunchKernelGGL(gemm_out_sk, dim3(16, 16, 4), blk, 0, stream, og, Wob, pbuf);
    hipLaunchKernelGGL(reduce4, dim3(1024), blk, 0, stream, pbuf, out);
}